// Round 1
// baseline (641.585 us; speedup 1.0000x reference)
//
#include <hip/hip_runtime.h>
#include <math.h>

typedef unsigned long long u64;
typedef unsigned int u32;

#define N_TOK 16384
#define DIM   256
#define KCB   4096

// ---- workspace layout (bytes) ----
#define WS_ROWMIN   0         // u64[16384] = 131072
#define WS_COLMIN   131072    // u64[4096]  = 32768   (0xFF region: [0,163840))
#define WS_CNT      163840    // float[4096]
#define WS_CPART    180224    // float[256]
#define WS_TOTAL    181248    // float[1]
#define WS_FLAG     181252    // int[1]   (written by detect kernel)
#define WS_F2       181312    // float[16384]
#define WS_C2       246848    // float[4096]
#define WS_END      263232

// ---- d_out layout (float elements) ----
#define OUT_FEAT    0
#define OUT_ASSIGN  4194304
#define OUT_CLOSS   4210688
#define OUT_UPCT    4210689
#define OUT_COUNT   4210690
#define OUT_AVG     4214786
#define OUT_CB      4218882   // also reused as feat_sum scratch (zeroed first)

// (float)(1.0 - 0.99) as jnp computes it (f64 -> f32 weak scalar)
#define C_1MG 0.009999999776482582f

__device__ __forceinline__ u32 fkey(float d) {
    u32 u = __float_as_uint(d);
    return (u & 0x80000000u) ? ~u : (u | 0x80000000u);
}
__device__ __forceinline__ u64 u64min(u64 a, u64 b) { return a < b ? a : b; }
__device__ __forceinline__ u64 shflxor64(u64 v, int m) {
    int lo = __shfl_xor((int)(u32)(v & 0xFFFFFFFFULL), m, 64);
    int hi = __shfl_xor((int)(u32)(v >> 32), m, 64);
    return ((u64)(u32)hi << 32) | (u32)lo;
}
__device__ __forceinline__ bool read_mask(const void* mp, int flag, int n) {
    if (flag == 2) return ((const float*)mp)[n] != 0.0f;
    if (flag == 1) return ((const int*)mp)[n] != 0;
    return ((const unsigned char*)mp)[n] != 0;
}

// Detect mask storage layout: 0 = uint8, 1 = int32, 2 = float32
__global__ void k_detect(const void* __restrict__ mp, int* __restrict__ flag) {
    if (threadIdx.x == 0) {
        const u32* w = (const u32*)mp;
        bool allf = true, alli = true, any1 = false;
        for (int i = 0; i < 64; ++i) {
            u32 x = w[i];
            if (x != 0u && x != 0x3F800000u) allf = false;
            if (x == 0x3F800000u) any1 = true;
            if (x > 1u) alli = false;
        }
        *flag = (allf && any1) ? 2 : (alli ? 1 : 0);
    }
}

// f2[n] = mask ? ||f_n||^2 : +inf ;  c2[k] = ||c_k||^2
__global__ __launch_bounds__(256)
void k_norms(const float* __restrict__ F, const float* __restrict__ CB,
             const void* __restrict__ mp, const int* __restrict__ flagp,
             float* __restrict__ f2, float* __restrict__ c2) {
    __shared__ float red[4];
    const int b = blockIdx.x, d = threadIdx.x;
    const float* src = (b < N_TOK) ? (F + (size_t)b * DIM) : (CB + (size_t)(b - N_TOK) * DIM);
    float v = src[d];
    float s = v * v;
#pragma unroll
    for (int m = 32; m > 0; m >>= 1) s += __shfl_xor(s, m, 64);
    if ((d & 63) == 0) red[d >> 6] = s;
    __syncthreads();
    if (d == 0) {
        float tot = red[0] + red[1] + red[2] + red[3];
        if (b < N_TOK) {
            bool msk = read_mask(mp, *flagp, b);
            f2[b] = msk ? tot : __builtin_huge_valf();
        } else {
            c2[b - N_TOK] = tot;
        }
    }
}

// Fused distance GEMM + dual argmin.
// grid (128, 8): x = token panel of 128, y = 512-code segment. block = 256 thr.
__global__ __launch_bounds__(256, 2)
void k_gemm(const float* __restrict__ F, const float* __restrict__ CB,
            const float* __restrict__ f2, const float* __restrict__ c2,
            u64* __restrict__ rowmin, u64* __restrict__ colmin) {
    __shared__ float As[128][32];
    __shared__ float Bs[128][32];
    __shared__ u64 colred[4][128];

    const int t = threadIdx.x;
    const int ty = t >> 4, tx = t & 15;
    const int wave = t >> 6;
    const int rowbase = blockIdx.x * 128;
    const int kseg = blockIdx.y * 512;

    u64 rowbest[8];
#pragma unroll
    for (int i = 0; i < 8; ++i) rowbest[i] = ~0ULL;

    for (int c = 0; c < 4; ++c) {
        const int kbase = kseg + c * 128;
        float acc[8][8];
#pragma unroll
        for (int i = 0; i < 8; ++i)
#pragma unroll
            for (int j = 0; j < 8; ++j) acc[i][j] = 0.0f;

        for (int dc = 0; dc < 8; ++dc) {
            const int db = dc * 32;
#pragma unroll
            for (int i = 0; i < 4; ++i) {
                int g = t + i * 256;          // 0..1023
                int r = g >> 3;               // 8 float4 per row
                int d4 = (g & 7) << 2;
                int dsw = d4 ^ (((r >> 3) & 7) << 2);   // XOR swizzle, bank-safe reads
                float4 va = *(const float4*)(F + (size_t)(rowbase + r) * DIM + db + d4);
                *(float4*)&As[r][dsw] = va;
                float4 vb = *(const float4*)(CB + (size_t)(kbase + r) * DIM + db + d4);
                *(float4*)&Bs[r][dsw] = vb;
            }
            __syncthreads();
#pragma unroll
            for (int dd = 0; dd < 32; dd += 4) {
                float4 a[8], b[8];
#pragma unroll
                for (int i = 0; i < 8; ++i)
                    a[i] = *(const float4*)&As[ty * 8 + i][dd ^ ((ty & 7) << 2)];
#pragma unroll
                for (int j = 0; j < 8; ++j)
                    b[j] = *(const float4*)&Bs[tx * 8 + j][dd ^ ((tx & 7) << 2)];
#pragma unroll
                for (int i = 0; i < 8; ++i)
#pragma unroll
                    for (int j = 0; j < 8; ++j) {
                        acc[i][j] = fmaf(a[i].x, b[j].x, acc[i][j]);
                        acc[i][j] = fmaf(a[i].y, b[j].y, acc[i][j]);
                        acc[i][j] = fmaf(a[i].z, b[j].z, acc[i][j]);
                        acc[i][j] = fmaf(a[i].w, b[j].w, acc[i][j]);
                    }
            }
            __syncthreads();
        }

        // epilogue: distances + running argmins
        float c2k[8], f2r[8];
#pragma unroll
        for (int j = 0; j < 8; ++j) c2k[j] = c2[kbase + tx * 8 + j];
#pragma unroll
        for (int i = 0; i < 8; ++i) f2r[i] = f2[rowbase + ty * 8 + i];
        u64 cbst[8];
#pragma unroll
        for (int j = 0; j < 8; ++j) cbst[j] = ~0ULL;
#pragma unroll
        for (int i = 0; i < 8; ++i) {
#pragma unroll
            for (int j = 0; j < 8; ++j) {
                float dist = (f2r[i] - 2.0f * acc[i][j]) + c2k[j];
                u64 hk = (u64)fkey(dist) << 32;
                rowbest[i] = u64min(rowbest[i], hk | (u32)(kbase + tx * 8 + j));
                cbst[j]    = u64min(cbst[j],    hk | (u32)(rowbase + ty * 8 + i));
            }
        }
        // column reduce: over ty within wave (lanes differ by 16/32), then across waves
#pragma unroll
        for (int j = 0; j < 8; ++j) {
            cbst[j] = u64min(cbst[j], shflxor64(cbst[j], 16));
            cbst[j] = u64min(cbst[j], shflxor64(cbst[j], 32));
        }
        if ((t & 63) < 16) {
#pragma unroll
            for (int j = 0; j < 8; ++j) colred[wave][tx * 8 + j] = cbst[j];
        }
        __syncthreads();
        if (t < 128) {
            u64 m = u64min(u64min(colred[0][t], colred[1][t]),
                           u64min(colred[2][t], colred[3][t]));
            atomicMin(&colmin[kbase + t], m);
        }
        __syncthreads();
    }

    // row reduce across tx (lanes differ by 1,2,4,8)
#pragma unroll
    for (int i = 0; i < 8; ++i) {
        u64 r = rowbest[i];
        r = u64min(r, shflxor64(r, 1));
        r = u64min(r, shflxor64(r, 2));
        r = u64min(r, shflxor64(r, 4));
        r = u64min(r, shflxor64(r, 8));
        if (tx == 0) atomicMin(&rowmin[rowbase + ty * 8 + i], r);
    }
}

// Per-token: out_features, assign, commitment partials, counts, feat_sum scatter
__global__ __launch_bounds__(256)
void k_token(const float* __restrict__ F, const float* __restrict__ CB,
             const u64* __restrict__ rowmin, const void* __restrict__ mp,
             const int* __restrict__ flagp,
             float* __restrict__ out_feat, float* __restrict__ out_assign,
             float* __restrict__ cnt, float* __restrict__ fsum,
             float* __restrict__ cpart) {
    __shared__ float red[4];
    const int n = blockIdx.x, d = threadIdx.x;
    const int k = (int)(u32)(rowmin[n] & 0xFFFFFFFFULL);
    const float f = F[(size_t)n * DIM + d];
    const float cv = CB[(size_t)k * DIM + d];
    out_feat[(size_t)n * DIM + d] = (cv + f) - f;   // mirror STE rounding
    const float df = cv - f;
    float s = df * df;
#pragma unroll
    for (int m = 32; m > 0; m >>= 1) s += __shfl_xor(s, m, 64);
    if ((d & 63) == 0) red[d >> 6] = s;
    __syncthreads();
    atomicAdd(&fsum[(size_t)k * DIM + d], f);       // unmasked, as in source
    if (d == 0) {
        out_assign[n] = (float)k;
        bool msk = read_mask(mp, *flagp, n);
        if (msk) {
            float tot = red[0] + red[1] + red[2] + red[3];
            atomicAdd(&cnt[k], 1.0f);
            atomicAdd(&cpart[n & 255], tot * (1.0f / 256.0f));
        }
    }
}

// total, commitment_loss, unassigned_percent
__global__ __launch_bounds__(256)
void k_scalars(const float* __restrict__ cnt, const float* __restrict__ cpart,
               float* __restrict__ totf, float* __restrict__ out) {
    __shared__ float redf[4], redc[4];
    __shared__ int redi[4];
    const int t = threadIdx.x;
    float ts = 0.0f;
    int asg = 0;
    for (int i = t; i < KCB; i += 256) {
        float v = cnt[i];
        ts += v;
        asg += (v > 0.0f) ? 1 : 0;
    }
    float cs = cpart[t];
#pragma unroll
    for (int m = 32; m > 0; m >>= 1) {
        ts += __shfl_xor(ts, m, 64);
        cs += __shfl_xor(cs, m, 64);
        asg += __shfl_xor(asg, m, 64);
    }
    if ((t & 63) == 0) { redf[t >> 6] = ts; redc[t >> 6] = cs; redi[t >> 6] = asg; }
    __syncthreads();
    if (t == 0) {
        float total = redf[0] + redf[1] + redf[2] + redf[3];
        total = fmaxf(total, 1.0f);
        float closs = (redc[0] + redc[1] + redc[2] + redc[3]) / total;
        int a = redi[0] + redi[1] + redi[2] + redi[3];
        totf[0] = total;
        out[OUT_CLOSS] = closs;
        out[OUT_UPCT] = (float)a / 4096.0f;
    }
}

// Codebook EMA update; fsum aliases out_cb (read-then-write per element)
__global__ __launch_bounds__(256)
void k_cbupd(const float* __restrict__ F, const float* __restrict__ CB,
             const float* __restrict__ cnt_in, const float* __restrict__ avg_in,
             const float* __restrict__ ac_, const float* __restrict__ fsum,
             const u64* __restrict__ colmin, const float* __restrict__ totf,
             float* __restrict__ out_count, float* __restrict__ out_avg,
             float* __restrict__ out_cb) {
    const int k = blockIdx.x, d = threadIdx.x;
    const float ac = ac_[k];
    const float total = totf[0];
    const float cn = C_1MG * ac + 0.99f * cnt_in[k];
    const float av = (C_1MG * ac) / total + 0.99f * avg_in[k];
    const float arg = ((-av * 4096.0f) * 10.0f) / C_1MG - 0.001f;
    const float alpha = expf(arg);
    const int tok = (int)(u32)(colmin[k] & 0xFFFFFFFFULL);
    const float cb = CB[(size_t)k * DIM + d];
    const float fs = fsum[(size_t)k * DIM + d];
    const float fr = F[(size_t)tok * DIM + d];
    const float assigned = (0.99f * cb + C_1MG * fs) / fmaxf(cn, 1.0f);
    const float unass = (1.0f - alpha) * cb + alpha * fr;
    const float nc = (ac < 1.0f) ? assigned : unass;   // reference's (buggy-looking) where()
    out_cb[(size_t)k * DIM + d] = cb + (cb - nc);      // prev + (prev - new)
    if (d == 0) { out_count[k] = cn; out_avg[k] = av; }
}

extern "C" void kernel_launch(void* const* d_in, const int* in_sizes, int n_in,
                              void* d_out, int out_size, void* d_ws, size_t ws_size,
                              hipStream_t stream) {
    const float* F   = (const float*)d_in[0];
    const void*  Mp  = d_in[1];
    const float* CB  = (const float*)d_in[2];
    const float* CNT = (const float*)d_in[3];
    const float* AVG = (const float*)d_in[4];
    float* out = (float*)d_out;
    char* ws = (char*)d_ws;
    if (ws_size < (size_t)WS_END) return;

    u64*   rowmin = (u64*)(ws + WS_ROWMIN);
    u64*   colmin = (u64*)(ws + WS_COLMIN);
    float* cnt    = (float*)(ws + WS_CNT);
    float* cpart  = (float*)(ws + WS_CPART);
    float* totf   = (float*)(ws + WS_TOTAL);
    int*   flag   = (int*)(ws + WS_FLAG);
    float* f2     = (float*)(ws + WS_F2);
    float* c2     = (float*)(ws + WS_C2);
    float* fsum   = out + OUT_CB;   // scratch in the new_codebook output region

    hipMemsetAsync(ws, 0xFF, 163840, stream);                       // rowmin+colmin
    hipMemsetAsync(ws + WS_CNT, 0, WS_FLAG - WS_CNT, stream);       // cnt,cpart,totf
    hipMemsetAsync(fsum, 0, (size_t)KCB * DIM * sizeof(float), stream);

    k_detect<<<1, 64, 0, stream>>>(Mp, flag);
    k_norms<<<N_TOK + KCB, 256, 0, stream>>>(F, CB, Mp, flag, f2, c2);
    k_gemm<<<dim3(128, 8), 256, 0, stream>>>(F, CB, f2, c2, rowmin, colmin);
    k_token<<<N_TOK, 256, 0, stream>>>(F, CB, rowmin, Mp, flag,
                                       out + OUT_FEAT, out + OUT_ASSIGN,
                                       cnt, fsum, cpart);
    k_scalars<<<1, 256, 0, stream>>>(cnt, cpart, totf, out);
    k_cbupd<<<KCB, 256, 0, stream>>>(F, CB, CNT, AVG, cnt, fsum, colmin, totf,
                                     out + OUT_COUNT, out + OUT_AVG, out + OUT_CB);
}

// Round 2
// 639.504 us; speedup vs baseline: 1.0033x; 1.0033x over previous
//
#include <hip/hip_runtime.h>
#include <math.h>

typedef unsigned long long u64;
typedef unsigned int u32;

#define N_TOK 16384
#define DIM   256
#define KCB   4096

// ---- workspace layout (bytes) ----
#define WS_ROWMIN   0         // u64[16384] = 131072
#define WS_COLMIN   131072    // u64[4096]  = 32768   (0xFF region: [0,163840))
#define WS_CNT      163840    // float[4096]
#define WS_CPART    180224    // float[256]
#define WS_TOTAL    181248    // float[1]
#define WS_FLAG     181252    // int[1]   (written by detect kernel)
#define WS_F2       181312    // float[16384]
#define WS_C2       246848    // float[4096]
#define WS_END      263232

// ---- d_out layout (float elements) ----
#define OUT_FEAT    0
#define OUT_ASSIGN  4194304
#define OUT_CLOSS   4210688
#define OUT_UPCT    4210689
#define OUT_COUNT   4210690
#define OUT_AVG     4214786
#define OUT_CB      4218882   // also reused as feat_sum scratch (zeroed first)

// (float)(1.0 - 0.99) as jnp computes it (f64 -> f32 weak scalar)
#define C_1MG 0.009999999776482582f

__device__ __forceinline__ u32 fkey(float d) {
    u32 u = __float_as_uint(d);
    return (u & 0x80000000u) ? ~u : (u | 0x80000000u);
}
__device__ __forceinline__ u64 u64min(u64 a, u64 b) { return a < b ? a : b; }
__device__ __forceinline__ u64 shflxor64(u64 v, int m) {
    int lo = __shfl_xor((int)(u32)(v & 0xFFFFFFFFULL), m, 64);
    int hi = __shfl_xor((int)(u32)(v >> 32), m, 64);
    return ((u64)(u32)hi << 32) | (u32)lo;
}
__device__ __forceinline__ bool read_mask(const void* mp, int flag, int n) {
    if (flag == 2) return ((const float*)mp)[n] != 0.0f;
    if (flag == 1) return ((const int*)mp)[n] != 0;
    return ((const unsigned char*)mp)[n] != 0;
}

// Detect mask storage layout: 0 = uint8, 1 = int32, 2 = float32
__global__ void k_detect(const void* __restrict__ mp, int* __restrict__ flag) {
    if (threadIdx.x == 0) {
        const u32* w = (const u32*)mp;
        bool allf = true, alli = true, any1 = false;
        for (int i = 0; i < 64; ++i) {
            u32 x = w[i];
            if (x != 0u && x != 0x3F800000u) allf = false;
            if (x == 0x3F800000u) any1 = true;
            if (x > 1u) alli = false;
        }
        *flag = (allf && any1) ? 2 : (alli ? 1 : 0);
    }
}

// f2[n] = mask ? ||f_n||^2 : +inf ;  c2[k] = ||c_k||^2
__global__ __launch_bounds__(256)
void k_norms(const float* __restrict__ F, const float* __restrict__ CB,
             const void* __restrict__ mp, const int* __restrict__ flagp,
             float* __restrict__ f2, float* __restrict__ c2) {
    __shared__ float red[4];
    const int b = blockIdx.x, d = threadIdx.x;
    const float* src = (b < N_TOK) ? (F + (size_t)b * DIM) : (CB + (size_t)(b - N_TOK) * DIM);
    float v = src[d];
    float s = v * v;
#pragma unroll
    for (int m = 32; m > 0; m >>= 1) s += __shfl_xor(s, m, 64);
    if ((d & 63) == 0) red[d >> 6] = s;
    __syncthreads();
    if (d == 0) {
        float tot = red[0] + red[1] + red[2] + red[3];
        if (b < N_TOK) {
            bool msk = read_mask(mp, *flagp, b);
            f2[b] = msk ? tot : __builtin_huge_valf();
        } else {
            c2[b - N_TOK] = tot;
        }
    }
}

// Fused distance GEMM + dual argmin.
// grid (N/128, K/128) = (128, 32); block = 256 threads; one 128x128 tile/block.
// Register budget: acc 64 + float2 frags 32 + addressing ~= 115 < 128.
__global__ __launch_bounds__(256, 4)
void k_gemm(const float* __restrict__ F, const float* __restrict__ CB,
            const float* __restrict__ f2, const float* __restrict__ c2,
            u64* __restrict__ rowmin, u64* __restrict__ colmin) {
    __shared__ float As[128][32];
    __shared__ float Bs[128][32];
    __shared__ u64 colred[4][128];

    const int t = threadIdx.x;
    const int ty = t >> 4, tx = t & 15;
    const int wave = t >> 6;
    const int rowbase = blockIdx.x * 128;
    const int kbase = blockIdx.y * 128;

    float acc[8][8];
#pragma unroll
    for (int i = 0; i < 8; ++i)
#pragma unroll
        for (int j = 0; j < 8; ++j) acc[i][j] = 0.0f;

    for (int dc = 0; dc < 8; ++dc) {
        const int db = dc * 32;
#pragma unroll
        for (int i = 0; i < 4; ++i) {
            int g = t + i * 256;              // 0..1023
            int r = g >> 3;                   // 8 float4 per 32-float row
            int c4 = (g & 7) << 2;
            int sw = c4 ^ (((r >> 3) & 7) << 2);   // XOR swizzle (4-float granular)
            *(float4*)&As[r][sw] = *(const float4*)(F + (size_t)(rowbase + r) * DIM + db + c4);
            *(float4*)&Bs[r][sw] = *(const float4*)(CB + (size_t)(kbase + r) * DIM + db + c4);
        }
        __syncthreads();
#pragma unroll
        for (int dd = 0; dd < 32; dd += 2) {
            float2 a[8], b[8];
#pragma unroll
            for (int i = 0; i < 8; ++i)
                a[i] = *(const float2*)&As[ty * 8 + i][dd ^ ((ty & 7) << 2)];
#pragma unroll
            for (int j = 0; j < 8; ++j)
                b[j] = *(const float2*)&Bs[tx * 8 + j][dd ^ ((tx & 7) << 2)];
#pragma unroll
            for (int i = 0; i < 8; ++i)
#pragma unroll
                for (int j = 0; j < 8; ++j) {
                    acc[i][j] = fmaf(a[i].x, b[j].x, acc[i][j]);
                    acc[i][j] = fmaf(a[i].y, b[j].y, acc[i][j]);
                }
        }
        __syncthreads();
    }

    // Epilogue: distances + dual argmin. Row-by-row to keep live set small.
    float c2k[8];
#pragma unroll
    for (int j = 0; j < 8; ++j) c2k[j] = c2[kbase + tx * 8 + j];
    u64 cbst[8];
#pragma unroll
    for (int j = 0; j < 8; ++j) cbst[j] = ~0ULL;

#pragma unroll
    for (int i = 0; i < 8; ++i) {
        const int row = rowbase + ty * 8 + i;
        const float f2r = f2[row];
        u64 rbst = ~0ULL;
#pragma unroll
        for (int j = 0; j < 8; ++j) {
            float dist = (f2r - 2.0f * acc[i][j]) + c2k[j];
            u64 hk = (u64)fkey(dist) << 32;
            rbst    = u64min(rbst, hk | (u32)(kbase + tx * 8 + j));
            cbst[j] = u64min(cbst[j], hk | (u32)row);
        }
        // row reduce across tx (lanes differ by 1,2,4,8)
        rbst = u64min(rbst, shflxor64(rbst, 1));
        rbst = u64min(rbst, shflxor64(rbst, 2));
        rbst = u64min(rbst, shflxor64(rbst, 4));
        rbst = u64min(rbst, shflxor64(rbst, 8));
        if (tx == 0) atomicMin(&rowmin[row], rbst);
    }

    // column reduce: over ty within wave (lanes differ by 16/32), then across waves
#pragma unroll
    for (int j = 0; j < 8; ++j) {
        cbst[j] = u64min(cbst[j], shflxor64(cbst[j], 16));
        cbst[j] = u64min(cbst[j], shflxor64(cbst[j], 32));
    }
    if ((t & 63) < 16) {
#pragma unroll
        for (int j = 0; j < 8; ++j) colred[wave][tx * 8 + j] = cbst[j];
    }
    __syncthreads();
    if (t < 128) {
        u64 m = u64min(u64min(colred[0][t], colred[1][t]),
                       u64min(colred[2][t], colred[3][t]));
        atomicMin(&colmin[kbase + t], m);
    }
}

// Per-token: out_features, assign, commitment partials, counts, feat_sum scatter
__global__ __launch_bounds__(256)
void k_token(const float* __restrict__ F, const float* __restrict__ CB,
             const u64* __restrict__ rowmin, const void* __restrict__ mp,
             const int* __restrict__ flagp,
             float* __restrict__ out_feat, float* __restrict__ out_assign,
             float* __restrict__ cnt, float* __restrict__ fsum,
             float* __restrict__ cpart) {
    __shared__ float red[4];
    const int n = blockIdx.x, d = threadIdx.x;
    const int k = (int)(u32)(rowmin[n] & 0xFFFFFFFFULL);
    const float f = F[(size_t)n * DIM + d];
    const float cv = CB[(size_t)k * DIM + d];
    out_feat[(size_t)n * DIM + d] = (cv + f) - f;   // mirror STE rounding
    const float df = cv - f;
    float s = df * df;
#pragma unroll
    for (int m = 32; m > 0; m >>= 1) s += __shfl_xor(s, m, 64);
    if ((d & 63) == 0) red[d >> 6] = s;
    __syncthreads();
    atomicAdd(&fsum[(size_t)k * DIM + d], f);       // unmasked, as in source
    if (d == 0) {
        out_assign[n] = (float)k;
        bool msk = read_mask(mp, *flagp, n);
        if (msk) {
            float tot = red[0] + red[1] + red[2] + red[3];
            atomicAdd(&cnt[k], 1.0f);
            atomicAdd(&cpart[n & 255], tot * (1.0f / 256.0f));
        }
    }
}

// total, commitment_loss, unassigned_percent
__global__ __launch_bounds__(256)
void k_scalars(const float* __restrict__ cnt, const float* __restrict__ cpart,
               float* __restrict__ totf, float* __restrict__ out) {
    __shared__ float redf[4], redc[4];
    __shared__ int redi[4];
    const int t = threadIdx.x;
    float ts = 0.0f;
    int asg = 0;
    for (int i = t; i < KCB; i += 256) {
        float v = cnt[i];
        ts += v;
        asg += (v > 0.0f) ? 1 : 0;
    }
    float cs = cpart[t];
#pragma unroll
    for (int m = 32; m > 0; m >>= 1) {
        ts += __shfl_xor(ts, m, 64);
        cs += __shfl_xor(cs, m, 64);
        asg += __shfl_xor(asg, m, 64);
    }
    if ((t & 63) == 0) { redf[t >> 6] = ts; redc[t >> 6] = cs; redi[t >> 6] = asg; }
    __syncthreads();
    if (t == 0) {
        float total = redf[0] + redf[1] + redf[2] + redf[3];
        total = fmaxf(total, 1.0f);
        float closs = (redc[0] + redc[1] + redc[2] + redc[3]) / total;
        int a = redi[0] + redi[1] + redi[2] + redi[3];
        totf[0] = total;
        out[OUT_CLOSS] = closs;
        out[OUT_UPCT] = (float)a / 4096.0f;
    }
}

// Codebook EMA update; fsum aliases out_cb (read-then-write per element)
__global__ __launch_bounds__(256)
void k_cbupd(const float* __restrict__ F, const float* __restrict__ CB,
             const float* __restrict__ cnt_in, const float* __restrict__ avg_in,
             const float* __restrict__ ac_, const float* __restrict__ fsum,
             const u64* __restrict__ colmin, const float* __restrict__ totf,
             float* __restrict__ out_count, float* __restrict__ out_avg,
             float* __restrict__ out_cb) {
    const int k = blockIdx.x, d = threadIdx.x;
    const float ac = ac_[k];
    const float total = totf[0];
    const float cn = C_1MG * ac + 0.99f * cnt_in[k];
    const float av = (C_1MG * ac) / total + 0.99f * avg_in[k];
    const float arg = ((-av * 4096.0f) * 10.0f) / C_1MG - 0.001f;
    const float alpha = expf(arg);
    const int tok = (int)(u32)(colmin[k] & 0xFFFFFFFFULL);
    const float cb = CB[(size_t)k * DIM + d];
    const float fs = fsum[(size_t)k * DIM + d];
    const float fr = F[(size_t)tok * DIM + d];
    const float assigned = (0.99f * cb + C_1MG * fs) / fmaxf(cn, 1.0f);
    const float unass = (1.0f - alpha) * cb + alpha * fr;
    const float nc = (ac < 1.0f) ? assigned : unass;   // reference's where()
    out_cb[(size_t)k * DIM + d] = cb + (cb - nc);      // prev + (prev - new)
    if (d == 0) { out_count[k] = cn; out_avg[k] = av; }
}

extern "C" void kernel_launch(void* const* d_in, const int* in_sizes, int n_in,
                              void* d_out, int out_size, void* d_ws, size_t ws_size,
                              hipStream_t stream) {
    const float* F   = (const float*)d_in[0];
    const void*  Mp  = d_in[1];
    const float* CB  = (const float*)d_in[2];
    const float* CNT = (const float*)d_in[3];
    const float* AVG = (const float*)d_in[4];
    float* out = (float*)d_out;
    char* ws = (char*)d_ws;
    if (ws_size < (size_t)WS_END) return;

    u64*   rowmin = (u64*)(ws + WS_ROWMIN);
    u64*   colmin = (u64*)(ws + WS_COLMIN);
    float* cnt    = (float*)(ws + WS_CNT);
    float* cpart  = (float*)(ws + WS_CPART);
    float* totf   = (float*)(ws + WS_TOTAL);
    int*   flag   = (int*)(ws + WS_FLAG);
    float* f2     = (float*)(ws + WS_F2);
    float* c2     = (float*)(ws + WS_C2);
    float* fsum   = out + OUT_CB;   // scratch in the new_codebook output region

    hipMemsetAsync(ws, 0xFF, 163840, stream);                       // rowmin+colmin
    hipMemsetAsync(ws + WS_CNT, 0, WS_FLAG - WS_CNT, stream);       // cnt,cpart,totf
    hipMemsetAsync(fsum, 0, (size_t)KCB * DIM * sizeof(float), stream);

    k_detect<<<1, 64, 0, stream>>>(Mp, flag);
    k_norms<<<N_TOK + KCB, 256, 0, stream>>>(F, CB, Mp, flag, f2, c2);
    k_gemm<<<dim3(128, 32), 256, 0, stream>>>(F, CB, f2, c2, rowmin, colmin);
    k_token<<<N_TOK, 256, 0, stream>>>(F, CB, rowmin, Mp, flag,
                                       out + OUT_FEAT, out + OUT_ASSIGN,
                                       cnt, fsum, cpart);
    k_scalars<<<1, 256, 0, stream>>>(cnt, cpart, totf, out);
    k_cbupd<<<KCB, 256, 0, stream>>>(F, CB, CNT, AVG, cnt, fsum, colmin, totf,
                                     out + OUT_COUNT, out + OUT_AVG, out + OUT_CB);
}

// Round 3
// 597.144 us; speedup vs baseline: 1.0744x; 1.0709x over previous
//
#include <hip/hip_runtime.h>
#include <math.h>

typedef unsigned long long u64;
typedef unsigned int u32;

#define N_TOK 16384
#define DIM   256
#define KCB   4096

// ---- workspace layout (bytes) ----
#define WS_ROWMIN   0         // u64[16384] = 131072
#define WS_COLMIN   131072    // u64[4096]  = 32768   (0xFF region: [0,163840))
#define WS_CNT      163840    // float[4096]
#define WS_CPART    180224    // float[256]
#define WS_TOTAL    181248    // float[1]
#define WS_FLAG     181252    // int[1]   (written by detect kernel)
#define WS_F2       181312    // float[16384]
#define WS_C2       246848    // float[4096]
#define WS_END      263232

// ---- d_out layout (float elements) ----
#define OUT_FEAT    0
#define OUT_ASSIGN  4194304
#define OUT_CLOSS   4210688
#define OUT_UPCT    4210689
#define OUT_COUNT   4210690
#define OUT_AVG     4214786
#define OUT_CB      4218882   // also reused as feat_sum scratch (zeroed first)

// (float)(1.0 - 0.99) as jnp computes it (f64 -> f32 weak scalar)
#define C_1MG 0.009999999776482582f

__device__ __forceinline__ u32 fkey(float d) {
    u32 u = __float_as_uint(d);
    return (u & 0x80000000u) ? ~u : (u | 0x80000000u);
}
__device__ __forceinline__ u64 u64min(u64 a, u64 b) { return a < b ? a : b; }
__device__ __forceinline__ u64 shflxor64(u64 v, int m) {
    int lo = __shfl_xor((int)(u32)(v & 0xFFFFFFFFULL), m, 64);
    int hi = __shfl_xor((int)(u32)(v >> 32), m, 64);
    return ((u64)(u32)hi << 32) | (u32)lo;
}
__device__ __forceinline__ bool read_mask(const void* mp, int flag, int n) {
    if (flag == 2) return ((const float*)mp)[n] != 0.0f;
    if (flag == 1) return ((const int*)mp)[n] != 0;
    return ((const unsigned char*)mp)[n] != 0;
}
// async global->LDS, 16B per lane; lds dest must be wave-uniform base (+lane*16 implicit)
__device__ __forceinline__ void gload_lds16(const float* g, void* l) {
    __builtin_amdgcn_global_load_lds((const __attribute__((address_space(1))) void*)g,
                                     (__attribute__((address_space(3))) void*)l,
                                     16, 0, 0);
}

// Detect mask storage layout: 0 = uint8, 1 = int32, 2 = float32
__global__ void k_detect(const void* __restrict__ mp, int* __restrict__ flag) {
    if (threadIdx.x == 0) {
        const u32* w = (const u32*)mp;
        bool allf = true, alli = true, any1 = false;
        for (int i = 0; i < 64; ++i) {
            u32 x = w[i];
            if (x != 0u && x != 0x3F800000u) allf = false;
            if (x == 0x3F800000u) any1 = true;
            if (x > 1u) alli = false;
        }
        *flag = (allf && any1) ? 2 : (alli ? 1 : 0);
    }
}

// f2[n] = mask ? ||f_n||^2 : +inf ;  c2[k] = ||c_k||^2
__global__ __launch_bounds__(256)
void k_norms(const float* __restrict__ F, const float* __restrict__ CB,
             const void* __restrict__ mp, const int* __restrict__ flagp,
             float* __restrict__ f2, float* __restrict__ c2) {
    __shared__ float red[4];
    const int b = blockIdx.x, d = threadIdx.x;
    const float* src = (b < N_TOK) ? (F + (size_t)b * DIM) : (CB + (size_t)(b - N_TOK) * DIM);
    float v = src[d];
    float s = v * v;
#pragma unroll
    for (int m = 32; m > 0; m >>= 1) s += __shfl_xor(s, m, 64);
    if ((d & 63) == 0) red[d >> 6] = s;
    __syncthreads();
    if (d == 0) {
        float tot = red[0] + red[1] + red[2] + red[3];
        if (b < N_TOK) {
            bool msk = read_mask(mp, *flagp, b);
            f2[b] = msk ? tot : __builtin_huge_valf();
        } else {
            c2[b - N_TOK] = tot;
        }
    }
}

// Fused distance GEMM + dual argmin.
// grid (N/128, K/128) = (128, 32); block = 512 threads; 128x128 tile/block.
// Per-thread: acc[4][8] (32 VGPR) + float2 frags (24) -> no spill pressure.
// Staging via global_load_lds with pre-swizzled GLOBAL source columns:
// LDS[r][x] = global[r][x ^ sw(r)], identical image to a swizzled ds_write.
__global__ __launch_bounds__(512, 2)
void k_gemm(const float* __restrict__ F, const float* __restrict__ CB,
            const float* __restrict__ f2, const float* __restrict__ c2,
            u64* __restrict__ rowmin, u64* __restrict__ colmin) {
    __shared__ float As[128][32];
    __shared__ float Bs[128][32];
    __shared__ u64 colred[8][128];

    const int t = threadIdx.x;          // 0..511
    const int tx = t & 15;              // 16 col-groups of 8 codes
    const int ty = t >> 4;              // 32 row-groups of 4 tokens
    const int wave = t >> 6;            // 0..7
    const int rowbase = blockIdx.x * 128;
    const int kbase = blockIdx.y * 128;

    // staging geometry: instr pair (g0 = t, g1 = 512+t), r = g>>3, 8 float4 per 32-float row
    const int g0 = t, g1 = 512 + t;
    const int r0 = g0 >> 3;
    const int r1 = g1 >> 3;
    const int c0 = ((g0 & 7) << 2) ^ (((g0 >> 6) & 7) << 2);  // source col pre-swizzle
    const int c1 = ((g1 & 7) << 2) ^ (((g1 >> 6) & 7) << 2);
    const float* Fb = F + (size_t)rowbase * DIM;
    const float* Cb = CB + (size_t)kbase * DIM;
    char* AsB = (char*)As;
    char* BsB = (char*)Bs;
    const int ldsA0 = wave * 1024;           // bytes; lanes add lane*16 implicitly
    const int ldsA1 = 8192 + wave * 1024;

    float acc[4][8];
#pragma unroll
    for (int i = 0; i < 4; ++i)
#pragma unroll
        for (int j = 0; j < 8; ++j) acc[i][j] = 0.0f;

    const int aswz = ((ty >> 1) & 7) << 2;   // row>>3 = ty>>1 for rows ty*4+i
    const int bswz = (tx & 7) << 2;          // row>>3 = tx for rows tx*8+j

    for (int dc = 0; dc < 8; ++dc) {
        const int db = dc * 32;
        gload_lds16(Fb + (size_t)r0 * DIM + db + c0, AsB + ldsA0);
        gload_lds16(Fb + (size_t)r1 * DIM + db + c1, AsB + ldsA1);
        gload_lds16(Cb + (size_t)r0 * DIM + db + c0, BsB + ldsA0);
        gload_lds16(Cb + (size_t)r1 * DIM + db + c1, BsB + ldsA1);
        __syncthreads();   // drains vmcnt(0): LDS image complete
#pragma unroll
        for (int dd = 0; dd < 32; dd += 2) {
            float2 a[4], b[8];
#pragma unroll
            for (int i = 0; i < 4; ++i)
                a[i] = *(const float2*)&As[ty * 4 + i][dd ^ aswz];
#pragma unroll
            for (int j = 0; j < 8; ++j)
                b[j] = *(const float2*)&Bs[tx * 8 + j][dd ^ bswz];
#pragma unroll
            for (int i = 0; i < 4; ++i)
#pragma unroll
                for (int j = 0; j < 8; ++j) {
                    acc[i][j] = fmaf(a[i].x, b[j].x, acc[i][j]);
                    acc[i][j] = fmaf(a[i].y, b[j].y, acc[i][j]);
                }
        }
        __syncthreads();   // all reads done before next chunk overwrites LDS
    }

    // Epilogue: distances + dual argmin. Row-by-row to keep live set small.
    float c2k[8];
#pragma unroll
    for (int j = 0; j < 8; ++j) c2k[j] = c2[kbase + tx * 8 + j];
    u64 cbst[8];
#pragma unroll
    for (int j = 0; j < 8; ++j) cbst[j] = ~0ULL;

#pragma unroll
    for (int i = 0; i < 4; ++i) {
        const int row = rowbase + ty * 4 + i;
        const float f2r = f2[row];
        u64 rbst = ~0ULL;
#pragma unroll
        for (int j = 0; j < 8; ++j) {
            float dist = (f2r - 2.0f * acc[i][j]) + c2k[j];
            u64 hk = (u64)fkey(dist) << 32;
            rbst    = u64min(rbst, hk | (u32)(kbase + tx * 8 + j));
            cbst[j] = u64min(cbst[j], hk | (u32)row);
        }
        // row reduce across tx (lanes differ by 1,2,4,8)
        rbst = u64min(rbst, shflxor64(rbst, 1));
        rbst = u64min(rbst, shflxor64(rbst, 2));
        rbst = u64min(rbst, shflxor64(rbst, 4));
        rbst = u64min(rbst, shflxor64(rbst, 8));
        if (tx == 0) atomicMin(&rowmin[row], rbst);
    }

    // column reduce: ty within wave via xor16/32, then across 8 waves via LDS
#pragma unroll
    for (int j = 0; j < 8; ++j) {
        cbst[j] = u64min(cbst[j], shflxor64(cbst[j], 16));
        cbst[j] = u64min(cbst[j], shflxor64(cbst[j], 32));
    }
    if ((t & 63) < 16) {
#pragma unroll
        for (int j = 0; j < 8; ++j) colred[wave][tx * 8 + j] = cbst[j];
    }
    __syncthreads();
    if (t < 128) {
        u64 m = colred[0][t];
#pragma unroll
        for (int w = 1; w < 8; ++w) m = u64min(m, colred[w][t]);
        atomicMin(&colmin[kbase + t], m);
    }
}

// Per-token: out_features, assign, commitment partials, counts, feat_sum scatter
__global__ __launch_bounds__(256)
void k_token(const float* __restrict__ F, const float* __restrict__ CB,
             const u64* __restrict__ rowmin, const void* __restrict__ mp,
             const int* __restrict__ flagp,
             float* __restrict__ out_feat, float* __restrict__ out_assign,
             float* __restrict__ cnt, float* __restrict__ fsum,
             float* __restrict__ cpart) {
    __shared__ float red[4];
    const int n = blockIdx.x, d = threadIdx.x;
    const int k = (int)(u32)(rowmin[n] & 0xFFFFFFFFULL);
    const float f = F[(size_t)n * DIM + d];
    const float cv = CB[(size_t)k * DIM + d];
    out_feat[(size_t)n * DIM + d] = (cv + f) - f;   // mirror STE rounding
    const float df = cv - f;
    float s = df * df;
#pragma unroll
    for (int m = 32; m > 0; m >>= 1) s += __shfl_xor(s, m, 64);
    if ((d & 63) == 0) red[d >> 6] = s;
    __syncthreads();
    atomicAdd(&fsum[(size_t)k * DIM + d], f);       // unmasked, as in source
    if (d == 0) {
        out_assign[n] = (float)k;
        bool msk = read_mask(mp, *flagp, n);
        if (msk) {
            float tot = red[0] + red[1] + red[2] + red[3];
            atomicAdd(&cnt[k], 1.0f);
            atomicAdd(&cpart[n & 255], tot * (1.0f / 256.0f));
        }
    }
}

// total, commitment_loss, unassigned_percent
__global__ __launch_bounds__(256)
void k_scalars(const float* __restrict__ cnt, const float* __restrict__ cpart,
               float* __restrict__ totf, float* __restrict__ out) {
    __shared__ float redf[4], redc[4];
    __shared__ int redi[4];
    const int t = threadIdx.x;
    float ts = 0.0f;
    int asg = 0;
    for (int i = t; i < KCB; i += 256) {
        float v = cnt[i];
        ts += v;
        asg += (v > 0.0f) ? 1 : 0;
    }
    float cs = cpart[t];
#pragma unroll
    for (int m = 32; m > 0; m >>= 1) {
        ts += __shfl_xor(ts, m, 64);
        cs += __shfl_xor(cs, m, 64);
        asg += __shfl_xor(asg, m, 64);
    }
    if ((t & 63) == 0) { redf[t >> 6] = ts; redc[t >> 6] = cs; redi[t >> 6] = asg; }
    __syncthreads();
    if (t == 0) {
        float total = redf[0] + redf[1] + redf[2] + redf[3];
        total = fmaxf(total, 1.0f);
        float closs = (redc[0] + redc[1] + redc[2] + redc[3]) / total;
        int a = redi[0] + redi[1] + redi[2] + redi[3];
        totf[0] = total;
        out[OUT_CLOSS] = closs;
        out[OUT_UPCT] = (float)a / 4096.0f;
    }
}

// Codebook EMA update; fsum aliases out_cb (read-then-write per element)
__global__ __launch_bounds__(256)
void k_cbupd(const float* __restrict__ F, const float* __restrict__ CB,
             const float* __restrict__ cnt_in, const float* __restrict__ avg_in,
             const float* __restrict__ ac_, const float* __restrict__ fsum,
             const u64* __restrict__ colmin, const float* __restrict__ totf,
             float* __restrict__ out_count, float* __restrict__ out_avg,
             float* __restrict__ out_cb) {
    const int k = blockIdx.x, d = threadIdx.x;
    const float ac = ac_[k];
    const float total = totf[0];
    const float cn = C_1MG * ac + 0.99f * cnt_in[k];
    const float av = (C_1MG * ac) / total + 0.99f * avg_in[k];
    const float arg = ((-av * 4096.0f) * 10.0f) / C_1MG - 0.001f;
    const float alpha = expf(arg);
    const int tok = (int)(u32)(colmin[k] & 0xFFFFFFFFULL);
    const float cb = CB[(size_t)k * DIM + d];
    const float fs = fsum[(size_t)k * DIM + d];
    const float fr = F[(size_t)tok * DIM + d];
    const float assigned = (0.99f * cb + C_1MG * fs) / fmaxf(cn, 1.0f);
    const float unass = (1.0f - alpha) * cb + alpha * fr;
    const float nc = (ac < 1.0f) ? assigned : unass;   // reference's where()
    out_cb[(size_t)k * DIM + d] = cb + (cb - nc);      // prev + (prev - new)
    if (d == 0) { out_count[k] = cn; out_avg[k] = av; }
}

extern "C" void kernel_launch(void* const* d_in, const int* in_sizes, int n_in,
                              void* d_out, int out_size, void* d_ws, size_t ws_size,
                              hipStream_t stream) {
    const float* F   = (const float*)d_in[0];
    const void*  Mp  = d_in[1];
    const float* CB  = (const float*)d_in[2];
    const float* CNT = (const float*)d_in[3];
    const float* AVG = (const float*)d_in[4];
    float* out = (float*)d_out;
    char* ws = (char*)d_ws;
    if (ws_size < (size_t)WS_END) return;

    u64*   rowmin = (u64*)(ws + WS_ROWMIN);
    u64*   colmin = (u64*)(ws + WS_COLMIN);
    float* cnt    = (float*)(ws + WS_CNT);
    float* cpart  = (float*)(ws + WS_CPART);
    float* totf   = (float*)(ws + WS_TOTAL);
    int*   flag   = (int*)(ws + WS_FLAG);
    float* f2     = (float*)(ws + WS_F2);
    float* c2     = (float*)(ws + WS_C2);
    float* fsum   = out + OUT_CB;   // scratch in the new_codebook output region

    hipMemsetAsync(ws, 0xFF, 163840, stream);                       // rowmin+colmin
    hipMemsetAsync(ws + WS_CNT, 0, WS_FLAG - WS_CNT, stream);       // cnt,cpart,totf
    hipMemsetAsync(fsum, 0, (size_t)KCB * DIM * sizeof(float), stream);

    k_detect<<<1, 64, 0, stream>>>(Mp, flag);
    k_norms<<<N_TOK + KCB, 256, 0, stream>>>(F, CB, Mp, flag, f2, c2);
    k_gemm<<<dim3(128, 32), 512, 0, stream>>>(F, CB, f2, c2, rowmin, colmin);
    k_token<<<N_TOK, 256, 0, stream>>>(F, CB, rowmin, Mp, flag,
                                       out + OUT_FEAT, out + OUT_ASSIGN,
                                       cnt, fsum, cpart);
    k_scalars<<<1, 256, 0, stream>>>(cnt, cpart, totf, out);
    k_cbupd<<<KCB, 256, 0, stream>>>(F, CB, CNT, AVG, cnt, fsum, colmin, totf,
                                     out + OUT_COUNT, out + OUT_AVG, out + OUT_CB);
}